// Round 16
// baseline (382.954 us; speedup 1.0000x reference)
//
#include <hip/hip_runtime.h>
#include <hip/hip_bf16.h>

#define DIMX 1024
#define HID  2048
#define NE   8
#define NT   4096
#define NPAIR 8192
#define MAXSTRIP 72

typedef __attribute__((ext_vector_type(8))) __bf16 bf16x8;
typedef __attribute__((ext_vector_type(4))) float f32x4;

__device__ inline unsigned short f2bf(float f) {
  union { float f; unsigned u; } v; v.f = f;
  unsigned r = v.u + 0x7FFFu + ((v.u >> 16) & 1u);
  return (unsigned short)(r >> 16);
}
__device__ inline float bf2f(unsigned short h) {
  union { unsigned u; float f; } v; v.u = ((unsigned)h) << 16;
  return v.f;
}

__device__ __forceinline__ void gload_lds16(const unsigned short* g, unsigned short* l) {
  __builtin_amdgcn_global_load_lds(
      (const __attribute__((address_space(1))) unsigned int*)g,
      (__attribute__((address_space(3))) unsigned int*)l, 16, 0, 0);
}

// ---------------- workspace layout (bytes) ----------------
#define O_CNT   0u
#define O_TOK   1024u
#define O_TK    132096u
#define O_PW    263168u
#define O_TI    394240u
#define O_TW    427008u
#define O_POFF  459776u
#define O_SE    459904u
#define O_SR0   460416u
#define O_XBF   524288u        // 4096*1024 bf16
#define O_W1T   16777216u      // 8*2048*1024 bf16 — DEAD after k_gemm1; reused as ybufB
#define O_W2T   50331648u      // 8*1024*2048 bf16
#define O_H     83886080u      // 9216*2048 bf16 (padded rows)
#define O_Y     121634816u     // 8192*1024 f32 (ybufA, split-K partial 0)

// fused: bf16-convert x row + gate logits + top-2 (one wave per token)
__global__ __launch_bounds__(256) void k_gate_cvt(const float* __restrict__ x,
                                                  const float* __restrict__ gw,
                                                  unsigned short* __restrict__ xbf,
                                                  int* __restrict__ ti,
                                                  float* __restrict__ tw) {
  int t = blockIdx.x * 4 + (threadIdx.x >> 6);
  int lane = threadIdx.x & 63;
  const float4* xr = (const float4*)(x + (size_t)t * DIMX);
  ushort4* xo = (ushort4*)(xbf + (size_t)t * DIMX);
  float p[NE];
#pragma unroll
  for (int e = 0; e < NE; e++) p[e] = 0.f;
#pragma unroll
  for (int j = 0; j < 4; j++) {
    int idx4 = j * 64 + lane;
    float4 v = xr[idx4];
    ushort4 o; o.x = f2bf(v.x); o.y = f2bf(v.y); o.z = f2bf(v.z); o.w = f2bf(v.w);
    xo[idx4] = o;
    const float4* gp = (const float4*)(gw + (size_t)(idx4 * 4) * NE);
    float4 gA = gp[0], gB = gp[1], gC = gp[2], gD = gp[3];
    float4 gE = gp[4], gF = gp[5], gG = gp[6], gH = gp[7];
    p[0] += v.x * gA.x + v.y * gC.x + v.z * gE.x + v.w * gG.x;
    p[1] += v.x * gA.y + v.y * gC.y + v.z * gE.y + v.w * gG.y;
    p[2] += v.x * gA.z + v.y * gC.z + v.z * gE.z + v.w * gG.z;
    p[3] += v.x * gA.w + v.y * gC.w + v.z * gE.w + v.w * gG.w;
    p[4] += v.x * gB.x + v.y * gD.x + v.z * gF.x + v.w * gH.x;
    p[5] += v.x * gB.y + v.y * gD.y + v.z * gF.y + v.w * gH.y;
    p[6] += v.x * gB.z + v.y * gD.z + v.z * gF.z + v.w * gH.z;
    p[7] += v.x * gB.w + v.y * gD.w + v.z * gF.w + v.w * gH.w;
  }
#pragma unroll
  for (int e = 0; e < NE; e++)
#pragma unroll
    for (int off = 32; off > 0; off >>= 1) p[e] += __shfl_xor(p[e], off);
  if (lane == 0) {
    int ia = 0; float va = p[0];
#pragma unroll
    for (int e = 1; e < NE; e++) if (p[e] > va) { va = p[e]; ia = e; }
    int ib = -1; float vb = -3.0e38f;
#pragma unroll
    for (int e = 0; e < NE; e++) { if (e == ia) continue; if (p[e] > vb) { vb = p[e]; ib = e; } }
    float w0 = 1.f / (1.f + expf(vb - va));
    ti[t * 2] = ia;     tw[t * 2] = w0;
    ti[t * 2 + 1] = ib; tw[t * 2 + 1] = 1.f - w0;
  }
}

// single block; ti AND tw staged in LDS -> zero global loads in the compaction loop
__global__ __launch_bounds__(512) void k_build(const int* __restrict__ ti,
                                               const float* __restrict__ tw,
                                               int* __restrict__ cnt,
                                               int* __restrict__ poffs,
                                               int* __restrict__ s_e, int* __restrict__ s_r0,
                                               int* __restrict__ ptok, int* __restrict__ ptk,
                                               float* __restrict__ pw) {
  __shared__ int sti[NPAIR];
  __shared__ float stw[NPAIR];
  __shared__ int scnt[NE];
  for (int i = threadIdx.x; i < NPAIR; i += 512) { sti[i] = ti[i]; stw[i] = tw[i]; }
  __syncthreads();
  int wid = threadIdx.x >> 6;
  int lane = threadIdx.x & 63;
  int c = 0;
  for (int p = lane; p < NPAIR; p += 64) c += (sti[p] == wid) ? 1 : 0;
#pragma unroll
  for (int off = 32; off > 0; off >>= 1) c += __shfl_xor(c, off);
  if (lane == 0) scnt[wid] = c;
  __syncthreads();
  if (threadIdx.x == 0) {
    int s = 0, pacc = 0;
    for (int e = 0; e < NE; e++) {
      cnt[e] = scnt[e];
      poffs[e] = pacc;
      int ns = (scnt[e] + 127) >> 7;
      for (int k = 0; k < ns; k++) { s_e[s] = e; s_r0[s] = k * 128; s++; }
      pacc += ns * 128;
    }
    poffs[NE] = pacc;
    for (; s < MAXSTRIP; s++) { s_e[s] = -1; s_r0[s] = 0; }
  }
  int base = 0;
  for (int p0 = 0; p0 < NPAIR; p0 += 64) {
    int p = p0 + lane;
    bool m = (sti[p] == wid);
    unsigned long long mask = __ballot(m);
    if (m) {
      int pos = base + __popcll(mask & ((1ull << lane) - 1ull));
      ptok[wid * NT + pos] = p >> 1;
      ptk[wid * NT + pos] = p;
      pw[wid * NT + pos] = stw[p];
    }
    base += __popcll(mask);
  }
}

// 64x64 transpose+convert: out[c][r] = bf16(in[r][c]), per expert slice
__global__ __launch_bounds__(256) void k_transpose_cvt(const float* __restrict__ in,
                                                       unsigned short* __restrict__ out,
                                                       int R, int C) {
  __shared__ float tile[64][73];
  int e = blockIdx.z;
  const float* ip = in + (size_t)e * R * C;
  unsigned short* op = out + (size_t)e * R * C;
  int c0 = blockIdx.x * 64, r0 = blockIdx.y * 64;
  int tx = threadIdx.x & 15, ty = threadIdx.x >> 4;
#pragma unroll
  for (int i = 0; i < 4; i++) {
    int row = ty + i * 16;
    float4 v = *(const float4*)(ip + (size_t)(r0 + row) * C + c0 + tx * 4);
    tile[row][tx * 4] = v.x; tile[row][tx * 4 + 1] = v.y;
    tile[row][tx * 4 + 2] = v.z; tile[row][tx * 4 + 3] = v.w;
  }
  __syncthreads();
  int rx = threadIdx.x & 15, cy = threadIdx.x >> 4;
  int r_off = rx * 4;
#pragma unroll
  for (int i = 0; i < 4; i++) {
    int cc = cy + i * 16;
    ushort4 h;
    h.x = f2bf(tile[r_off][cc]);     h.y = f2bf(tile[r_off + 1][cc]);
    h.z = f2bf(tile[r_off + 2][cc]); h.w = f2bf(tile[r_off + 3][cc]);
    *(ushort4*)(op + (size_t)(c0 + cc) * R + r0 + r_off) = h;
  }
}

#define BM 128
#define BN 128
#define BK 64
// R13: BK=64 — amortize the measured ~1100-1800 cyc/step fixed overhead
// (R8/R10/R12: per-step cost invariant under every sync-schedule change)
// over 2x the work: 16 K-steps instead of 32, 32 MFMA + 16 ds_read per
// wave-step in two sub-k halves (sub-k1 ds_reads hide under sub-k0 MFMAs).
// 2 LDS buffers (64 KB -> 2 blocks/CU = current effective residency),
// 2 barriers/step (required: cooperative staging + 2 buffers; R10<->R12
// proved barrier count is free), counted vmcnt(8).
// 128B-row swizzle (8 chunks of 16B): store phys chunk = lane&7, source
// logical chunk = (lane&7)^((lane>>3)&7); read phys = quad^(m16&7)
// (sub-k1: ^4). Per 16-lane phase: all 8 chunks x2 = 2-way = free (m136).
// XCD swizzle (T1) retained: 72 strips = 9/XCD.
#define KSTEPS 16

// GEMM1: hpre[poffs[e]+g][:] = gathered_x[tok] @ w1T[e]^T + b1[e]
__global__ __launch_bounds__(256) void k_gemm1(
    const unsigned short* __restrict__ xbf,
    const unsigned short* __restrict__ w1t,
    const float* __restrict__ bias1,
    const int* __restrict__ cnt, const int* __restrict__ s_e,
    const int* __restrict__ s_r0, const int* __restrict__ poffs,
    const int* __restrict__ ptok,
    unsigned short* __restrict__ hpre)
{
  int lid = blockIdx.x + 16 * blockIdx.y;      // 0..1151
  int xcd = lid & 7;
  int t4 = lid >> 3;                           // 0..143
  int colb = t4 & 15;
  int s = xcd * 9 + (t4 >> 4);                 // strip
  int e = s_e[s];
  if (e < 0) return;
  int r0e = s_r0[s];
  int n_e = cnt[e];
  int pbase = poffs[e];
  int col0 = colb * BN;

  __shared__ __align__(16) unsigned short As[2][BM][BK];
  __shared__ __align__(16) unsigned short Bs[2][BN][BK];

  int tid = threadIdx.x;
  int lane = tid & 63, wid = tid >> 6;
  int wr = wid >> 1, wc = wid & 1;
  int quad = lane >> 4, m16 = lane & 15;

  // staging: 8 instrs/wave/step; each covers 8 rows x 128B.
  // lane -> row (lane>>3), phys chunk lane&7; source logical chunk
  // (lane&7)^((lane>>3)&7)  [row&7 == (lane>>3)&7 since bases %8==0]
  int r8 = lane >> 3;
  int csrc = ((lane & 7) ^ r8) * 8;
  const unsigned short* ap[4];
  const unsigned short* bp[4];
  {
    const unsigned short* bbase = w1t + (size_t)e * HID * DIMX;
#pragma unroll
    for (int i = 0; i < 4; i++) {
      int ga = r0e + wid * 32 + i * 8 + r8; if (ga >= n_e) ga = n_e - 1;
      ap[i] = xbf + (size_t)ptok[e * NT + ga] * DIMX + csrc;
      bp[i] = bbase + (size_t)(col0 + wid * 32 + i * 8 + r8) * DIMX + csrc;
    }
  }

  int ca0 = (quad ^ (m16 & 7)) * 8;   // element offset of 16B chunk, sub-k0
  // sub-k1 logical chunk = quad+4 -> phys ^4 -> element offset ^32

  f32x4 acc[4][4];
#pragma unroll
  for (int i = 0; i < 4; i++)
#pragma unroll
    for (int j = 0; j < 4; j++) acc[i][j] = (f32x4)(0.f);

#define STAGE1(b, kk) do { \
    gload_lds16(ap[0] + (kk), &As[b][wid * 32 +  0][0]); \
    gload_lds16(ap[1] + (kk), &As[b][wid * 32 +  8][0]); \
    gload_lds16(ap[2] + (kk), &As[b][wid * 32 + 16][0]); \
    gload_lds16(ap[3] + (kk), &As[b][wid * 32 + 24][0]); \
    gload_lds16(bp[0] + (kk), &Bs[b][wid * 32 +  0][0]); \
    gload_lds16(bp[1] + (kk), &Bs[b][wid * 32 +  8][0]); \
    gload_lds16(bp[2] + (kk), &Bs[b][wid * 32 + 16][0]); \
    gload_lds16(bp[3] + (kk), &Bs[b][wid * 32 + 24][0]); \
  } while (0)

  STAGE1(0, 0);
  int cur = 0;
  for (int k = 0; k < KSTEPS; ++k) {
    // barrier1: all waves' reads of buf[cur^1] (iter k-1) retired -> safe to overwrite
    asm volatile("s_waitcnt lgkmcnt(0)" ::: "memory");
    __builtin_amdgcn_sched_barrier(0);
    __builtin_amdgcn_s_barrier();
    if (k + 1 < KSTEPS) {
      STAGE1(cur ^ 1, (k + 1) * BK);
      asm volatile("s_waitcnt vmcnt(8)" ::: "memory");   // my buf[cur] 8 loads retired
    } else {
      asm volatile("s_waitcnt vmcnt(0)" ::: "memory");
    }
    __builtin_amdgcn_sched_barrier(0);
    __builtin_amdgcn_s_barrier();            // barrier2: buf[cur] fully in LDS
    __builtin_amdgcn_sched_barrier(0);
    bf16x8 af[4], bfr[4];
#pragma unroll
    for (int i = 0; i < 4; i++) af[i]  = *(const bf16x8*)&As[cur][wr * 64 + i * 16 + m16][ca0];
#pragma unroll
    for (int j = 0; j < 4; j++) bfr[j] = *(const bf16x8*)&Bs[cur][wc * 64 + j * 16 + m16][ca0];
    __builtin_amdgcn_s_setprio(1);
#pragma unroll
    for (int i = 0; i < 4; i++)
#pragma unroll
      for (int j = 0; j < 4; j++)
        acc[i][j] = __builtin_amdgcn_mfma_f32_16x16x32_bf16(af[i], bfr[j], acc[i][j], 0, 0, 0);
    __builtin_amdgcn_s_setprio(0);
    bf16x8 ag[4], bgr[4];
#pragma unroll
    for (int i = 0; i < 4; i++) ag[i]  = *(const bf16x8*)&As[cur][wr * 64 + i * 16 + m16][ca0 ^ 32];
#pragma unroll
    for (int j = 0; j < 4; j++) bgr[j] = *(const bf16x8*)&Bs[cur][wc * 64 + j * 16 + m16][ca0 ^ 32];
    __builtin_amdgcn_s_setprio(1);
#pragma unroll
    for (int i = 0; i < 4; i++)
#pragma unroll
      for (int j = 0; j < 4; j++)
        acc[i][j] = __builtin_amdgcn_mfma_f32_16x16x32_bf16(ag[i], bgr[j], acc[i][j], 0, 0, 0);
    __builtin_amdgcn_s_setprio(0);
    cur ^= 1;
  }
#undef STAGE1

  float bj[4];
#pragma unroll
  for (int j = 0; j < 4; j++) bj[j] = bias1[e * HID + col0 + wc * 64 + j * 16 + m16];
#pragma unroll
  for (int i = 0; i < 4; i++) {
#pragma unroll
    for (int r = 0; r < 4; r++) {
      int g = r0e + wr * 64 + i * 16 + quad * 4 + r;
      if (g < n_e) {
        size_t rowbase = (size_t)(pbase + g) * HID;
#pragma unroll
        for (int j = 0; j < 4; j++) {
          int colg = col0 + wc * 64 + j * 16 + m16;
          hpre[rowbase + colg] = f2bf(acc[i][j][r] + bj[j]);
        }
      }
    }
  }
}

// one wave per row: LayerNorm + exact GELU over HID, no barriers
__global__ __launch_bounds__(256) void k_ln_gelu(unsigned short* __restrict__ h,
                                                 const float* __restrict__ g1,
                                                 const float* __restrict__ bb1,
                                                 const int* __restrict__ s_e) {
  int row = blockIdx.x * 4 + (threadIdx.x >> 6);
  int e = s_e[row >> 7];
  if (e < 0) return;
  int lane = threadIdx.x & 63;
  unsigned short* p = h + (size_t)row * HID;
  int4* p4 = (int4*)p;                 // 8 bf16 per int4; 256 per row
  int4 raw[4];
#pragma unroll
  for (int sg = 0; sg < 4; sg++) raw[sg] = p4[sg * 64 + lane];
  float v[32];
#pragma unroll
  for (int sg = 0; sg < 4; sg++) {
    const unsigned short* u = (const unsigned short*)&raw[sg];
#pragma unroll
    for (int k = 0; k < 8; k++) v[sg * 8 + k] = bf2f(u[k]);
  }
  float s = 0.f;
#pragma unroll
  for (int i = 0; i < 32; i++) s += v[i];
#pragma unroll
  for (int off = 32; off > 0; off >>= 1) s += __shfl_xor(s, off);
  float mean = s * (1.f / HID);
  float sq = 0.f;
#pragma unroll
  for (int i = 0; i < 32; i++) { float d = v[i] - mean; sq += d * d; }
#pragma unroll
  for (int off = 32; off > 0; off >>= 1) sq += __shfl_xor(sq, off);
  float rstd = rsqrtf(sq * (1.f / HID) + 1e-5f);
  const float4* gg = (const float4*)(g1 + (size_t)e * HID);
  const float4* gb = (const float4*)(bb1 + (size_t)e * HID);
#pragma unroll
  for (int sg = 0; sg < 4; sg++) {
    float4 ga = gg[sg * 128 + lane * 2], gc = gg[sg * 128 + lane * 2 + 1];
    float4 ba = gb[sg * 128 + lane * 2], bc = gb[sg * 128 + lane * 2 + 1];
    float gn[8] = {ga.x, ga.y, ga.z, ga.w, gc.x, gc.y, gc.z, gc.w};
    float bn[8] = {ba.x, ba.y, ba.z, ba.w, bc.x, bc.y, bc.z, bc.w};
    unsigned short o[8];
#pragma unroll
    for (int k = 0; k < 8; k++) {
      float xn = (v[sg * 8 + k] - mean) * rstd * gn[k] + bn[k];
      float ge = 0.5f * xn * (1.f + erff(xn * 0.7071067811865476f));
      o[k] = f2bf(ge);
    }
    p4[sg * 64 + lane] = *(const int4*)o;
  }
}

// GEMM2 (split-K x2): partial[ks][ptk] = (h_row @ w2T[e][:, ks*1024:+1024]^T
//                                          + (ks==1 ? b2[e] : 0)) * gate_weight
__global__ __launch_bounds__(256) void k_gemm2(
    const unsigned short* __restrict__ hb,
    const unsigned short* __restrict__ w2t,
    const float* __restrict__ bias2,
    const int* __restrict__ cnt, const int* __restrict__ s_e,
    const int* __restrict__ s_r0, const int* __restrict__ poffs,
    const int* __restrict__ ptk, const float* __restrict__ pw,
    float* __restrict__ ybufA, float* __restrict__ ybufB)
{
  int lid = blockIdx.x + 8 * (blockIdx.y + 72 * blockIdx.z);
  int xcd = lid & 7;
  int t4 = lid >> 3;                  // 0..143
  int colb = t4 & 7;
  int rem = t4 >> 3;                  // 0..17
  int ks = rem & 1;
  int s = xcd * 9 + (rem >> 1);       // strip
  int e = s_e[s];
  if (e < 0) return;
  int r0e = s_r0[s];
  int n_e = cnt[e];
  int pbase = poffs[e];
  int col0 = colb * BN;
  int kbase = ks << 10;               // element offset into K=2048

  __shared__ __align__(16) unsigned short As[2][BM][BK];
  __shared__ __align__(16) unsigned short Bs[2][BN][BK];

  int tid = threadIdx.x;
  int lane = tid & 63, wid = tid >> 6;
  int wr = wid >> 1, wc = wid & 1;
  int quad = lane >> 4, m16 = lane & 15;

  int r8 = lane >> 3;
  int csrc = ((lane & 7) ^ r8) * 8;
  const unsigned short* ap[4];
  const unsigned short* bp[4];
  {
    const unsigned short* bbase = w2t + (size_t)e * DIMX * HID;
#pragma unroll
    for (int i = 0; i < 4; i++) {
      int ga = r0e + wid * 32 + i * 8 + r8; if (ga >= n_e) ga = n_e - 1;
      ap[i] = hb + (size_t)(pbase + ga) * HID + kbase + csrc;
      bp[i] = bbase + (size_t)(col0 + wid * 32 + i * 8 + r8) * HID + kbase + csrc;
    }
  }

  int ca0 = (quad ^ (m16 & 7)) * 8;

  f32x4 acc[4][4];
#pragma unroll
  for (int i = 0; i < 4; i++)
#pragma unroll
    for (int j = 0; j < 4; j++) acc[i][j] = (f32x4)(0.f);

#define STAGE2(b, kk) do { \
    gload_lds16(ap[0] + (kk), &As[b][wid * 32 +  0][0]); \
    gload_lds16(ap[1] + (kk), &As[b][wid * 32 +  8][0]); \
    gload_lds16(ap[2] + (kk), &As[b][wid * 32 + 16][0]); \
    gload_lds16(ap[3] + (kk), &As[b][wid * 32 + 24][0]); \
    gload_lds16(bp[0] + (kk), &Bs[b][wid * 32 +  0][0]); \
    gload_lds16(bp[1] + (kk), &Bs[b][wid * 32 +  8][0]); \
    gload_lds16(bp[2] + (kk), &Bs[b][wid * 32 + 16][0]); \
    gload_lds16(bp[3] + (kk), &Bs[b][wid * 32 + 24][0]); \
  } while (0)

  STAGE2(0, 0);
  int cur = 0;
  for (int k = 0; k < KSTEPS; ++k) {
    asm volatile("s_waitcnt lgkmcnt(0)" ::: "memory");
    __builtin_amdgcn_sched_barrier(0);
    __builtin_amdgcn_s_barrier();
    if (k + 1 < KSTEPS) {
      STAGE2(cur ^ 1, (k + 1) * BK);
      asm volatile("s_waitcnt vmcnt(8)" ::: "memory");
    } else {
      asm volatile("s_waitcnt vmcnt(0)" ::: "memory");
    }
    __builtin_amdgcn_sched_barrier(0);
    __builtin_amdgcn_s_barrier();
    __builtin_amdgcn_sched_barrier(0);
    bf16x8 af[4], bfr[4];
#pragma unroll
    for (int i = 0; i < 4; i++) af[i]  = *(const bf16x8*)&As[cur][wr * 64 + i * 16 + m16][ca0];
#pragma unroll
    for (int j = 0; j < 4; j++) bfr[j] = *(const bf16x8*)&Bs[cur][wc * 64 + j * 16 + m16][ca0];
    __builtin_amdgcn_s_setprio(1);
#pragma unroll
    for (int i = 0; i < 4; i++)
#pragma unroll
      for (int j = 0; j < 4; j++)
        acc[i][j] = __builtin_amdgcn_mfma_f32_16x16x32_bf16(af[i], bfr[j], acc[i][j], 0, 0, 0);
    __builtin_amdgcn_s_setprio(0);
    bf16x8 ag[4], bgr[4];
#pragma unroll
    for (int i = 0; i < 4; i++) ag[i]  = *(const bf16x8*)&As[cur][wr * 64 + i * 16 + m16][ca0 ^ 32];
#pragma unroll
    for (int j = 0; j < 4; j++) bgr[j] = *(const bf16x8*)&Bs[cur][wc * 64 + j * 16 + m16][ca0 ^ 32];
    __builtin_amdgcn_s_setprio(1);
#pragma unroll
    for (int i = 0; i < 4; i++)
#pragma unroll
      for (int j = 0; j < 4; j++)
        acc[i][j] = __builtin_amdgcn_mfma_f32_16x16x32_bf16(ag[i], bgr[j], acc[i][j], 0, 0, 0);
    __builtin_amdgcn_s_setprio(0);
    cur ^= 1;
  }
#undef STAGE2

  float* yb = ks ? ybufB : ybufA;
  float bj[4];
#pragma unroll
  for (int j = 0; j < 4; j++)
    bj[j] = ks ? bias2[e * DIMX + col0 + wc * 64 + j * 16 + m16] : 0.f;
#pragma unroll
  for (int i = 0; i < 4; i++) {
#pragma unroll
    for (int r = 0; r < 4; r++) {
      int g = r0e + wr * 64 + i * 16 + quad * 4 + r;
      if (g < n_e) {
        int pi = e * NT + g;
        float w = pw[pi];
        size_t obase = (size_t)ptk[pi] * DIMX;
#pragma unroll
        for (int j = 0; j < 4; j++) {
          int colg = col0 + wc * 64 + j * 16 + m16;
          yb[obase + colg] = (acc[i][j][r] + bj[j]) * w;
        }
      }
    }
  }
}

// one wave per token: out = LN(yA_s0 + yA_s1 + yB_s0 + yB_s1 + x), no barriers
__global__ __launch_bounds__(256) void k_final(const float* __restrict__ ybA,
                                               const float* __restrict__ ybB,
                                               const float* __restrict__ x,
                                               const float* __restrict__ lg,
                                               const float* __restrict__ lb,
                                               float* __restrict__ out) {
  int t = blockIdx.x * 4 + (threadIdx.x >> 6);
  int lane = threadIdx.x & 63;
  const float4* yA0 = (const float4*)(ybA + (size_t)t * 2 * DIMX);
  const float4* yA1 = yA0 + DIMX / 4;
  const float4* yB0 = (const float4*)(ybB + (size_t)t * 2 * DIMX);
  const float4* yB1 = yB0 + DIMX / 4;
  const float4* x4 = (const float4*)(x + (size_t)t * DIMX);
  float4 v[4];
  float s = 0.f;
#pragma unroll
  for (int sg = 0; sg < 4; sg++) {
    int idx = sg * 64 + lane;
    float4 a = yA0[idx], b = yA1[idx], a2 = yB0[idx], b2 = yB1[idx], c = x4[idx];
    v[sg].x = a.x + b.x + a2.x + b2.x + c.x;
    v[sg].y = a.y + b.y + a2.y + b2.y + c.y;
    v[sg].z = a.z + b.z + a2.z + b2.z + c.z;
    v[sg].w = a.w + b.w + a2.w + b2.w + c.w;
    s += v[sg].x + v[sg].y + v[sg].z + v[sg].w;
  }
#pragma unroll
  for (int off = 32; off > 0; off >>= 1) s += __shfl_xor(s, off);
  float mean = s * (1.f / DIMX);
  float sq = 0.f;
#pragma unroll
  for (int sg = 0; sg < 4; sg++) {
    float dx = v[sg].x - mean, dy = v[sg].y - mean, dz = v[sg].z - mean, dw = v[sg].w - mean;
    sq += dx * dx + dy * dy + dz * dz + dw * dw;
  }
#pragma unroll
  for (int off = 32; off > 0; off >>= 1) sq += __shfl_xor(sq, off);
  float rstd = rsqrtf(sq * (1.f / DIMX) + 1e-5f);
  float4* o4 = (float4*)(out + (size_t)t * DIMX);
#pragma unroll
  for (int sg = 0; sg < 4; sg++) {
    int idx = sg * 64 + lane;
    float4 g = ((const float4*)lg)[idx], bb = ((const float4*)lb)[idx];
    float4 o;
    o.x = (v[sg].x - mean) * rstd * g.x + bb.x;
    o.y = (v[sg].y - mean) * rstd * g.y + bb.y;
    o.z = (v[sg].z - mean) * rstd * g.z + bb.z;
    o.w = (v[sg].w - mean) * rstd * g.w + bb.w;
    o4[idx] = o;
  }
}

extern "C" void kernel_launch(void* const* d_in, const int* in_sizes, int n_in,
                              void* d_out, int out_size, void* d_ws, size_t ws_size,
                              hipStream_t stream) {
  const float* x     = (const float*)d_in[0];
  const float* gw    = (const float*)d_in[1];
  const float* w1    = (const float*)d_in[2];
  const float* b1    = (const float*)d_in[3];
  const float* ln1g  = (const float*)d_in[4];
  const float* ln1b  = (const float*)d_in[5];
  const float* w2    = (const float*)d_in[6];
  const float* b2    = (const float*)d_in[7];
  const float* lng   = (const float*)d_in[8];
  const float* lnb   = (const float*)d_in[9];
  float* out = (float*)d_out;

  char* ws = (char*)d_ws;
  int* cnt   = (int*)(ws + O_CNT);
  int* ptok  = (int*)(ws + O_TOK);
  int* ptk   = (int*)(ws + O_TK);
  float* pw  = (float*)(ws + O_PW);
  int* ti    = (int*)(ws + O_TI);
  float* tw  = (float*)(ws + O_TW);
  int* poffs = (int*)(ws + O_POFF);
  int* s_e   = (int*)(ws + O_SE);
  int* s_r0  = (int*)(ws + O_SR0);
  unsigned short* xbf  = (unsigned short*)(ws + O_XBF);
  unsigned short* w1t  = (unsigned short*)(ws + O_W1T);
  unsigned short* w2t  = (unsigned short*)(ws + O_W2T);
  unsigned short* hpre = (unsigned short*)(ws + O_H);
  float* ybufA = (float*)(ws + O_Y);
  float* ybufB = (float*)(ws + O_W1T);   // w1t dead after k_gemm1; exact-size alias

  hipLaunchKernelGGL(k_gate_cvt, dim3(NT / 4), dim3(256), 0, stream, x, gw, xbf, ti, tw);
  hipLaunchKernelGGL(k_build, dim3(1), dim3(512), 0, stream, ti, tw, cnt, poffs, s_e, s_r0,
                     ptok, ptk, pw);
  hipLaunchKernelGGL(k_transpose_cvt, dim3(HID / 64, DIMX / 64, NE), dim3(256), 0, stream,
                     w1, w1t, DIMX, HID);
  hipLaunchKernelGGL(k_transpose_cvt, dim3(DIMX / 64, HID / 64, NE), dim3(256), 0, stream,
                     w2, w2t, HID, DIMX);
  hipLaunchKernelGGL(k_gemm1, dim3(HID / BN, MAXSTRIP), dim3(256), 0, stream,
                     xbf, w1t, b1, cnt, s_e, s_r0, poffs, ptok, hpre);
  hipLaunchKernelGGL(k_ln_gelu, dim3(MAXSTRIP * BM / 4), dim3(256), 0, stream,
                     hpre, ln1g, ln1b, s_e);
  hipLaunchKernelGGL(k_gemm2, dim3(DIMX / BN, MAXSTRIP, 2), dim3(256), 0, stream,
                     hpre, w2t, b2, cnt, s_e, s_r0, poffs, ptk, pw, ybufA, ybufB);
  hipLaunchKernelGGL(k_final, dim3(NT / 4), dim3(256), 0, stream, ybufA, ybufB, x, lng, lnb, out);
}

// Round 20
// 364.947 us; speedup vs baseline: 1.0493x; 1.0493x over previous
//
#include <hip/hip_runtime.h>
#include <hip/hip_bf16.h>

#define DIMX 1024
#define HID  2048
#define NE   8
#define NT   4096
#define NPAIR 8192
#define MAXSTRIP 72

typedef __attribute__((ext_vector_type(8))) __bf16 bf16x8;
typedef __attribute__((ext_vector_type(4))) float f32x4;

__device__ inline unsigned short f2bf(float f) {
  union { float f; unsigned u; } v; v.f = f;
  unsigned r = v.u + 0x7FFFu + ((v.u >> 16) & 1u);
  return (unsigned short)(r >> 16);
}
__device__ inline float bf2f(unsigned short h) {
  union { unsigned u; float f; } v; v.u = ((unsigned)h) << 16;
  return v.f;
}

__device__ __forceinline__ void gload_lds16(const unsigned short* g, unsigned short* l) {
  __builtin_amdgcn_global_load_lds(
      (const __attribute__((address_space(1))) unsigned int*)g,
      (__attribute__((address_space(3))) unsigned int*)l, 16, 0, 0);
}

// ---------------- workspace layout (bytes) ----------------
#define O_CNT   0u
#define O_TOK   1024u
#define O_TK    132096u
#define O_PW    263168u
#define O_TI    394240u
#define O_TW    427008u
#define O_POFF  459776u
#define O_SE    459904u
#define O_SR0   460416u
#define O_XBF   524288u        // 4096*1024 bf16
#define O_W1T   16777216u      // 8*2048*1024 bf16 — DEAD after k_gemm1; reused as ybufB
#define O_W2T   50331648u      // 8*1024*2048 bf16
#define O_H     83886080u      // 9216*2048 bf16 (padded rows)
#define O_Y     121634816u     // 8192*1024 f32 (ybufA, split-K partial 0)

// R16: fused prep — gate_cvt (1024 blocks) + transpose w1 (4096) +
// transpose w2 (4096) in ONE 9216-block launch. Independent work; saves 2
// launch gaps, better tail-fill, and makes the prep cost VISIBLE in the
// top-5 dispatch table (it was never profiled — bounded only <67 µs).
// Transpose writes upgraded to ushort8 (16B/lane, G13 sweet spot).
__global__ __launch_bounds__(256) void k_prep(const float* __restrict__ x,
                                              const float* __restrict__ gw,
                                              unsigned short* __restrict__ xbf,
                                              int* __restrict__ ti,
                                              float* __restrict__ tw,
                                              const float* __restrict__ w1,
                                              unsigned short* __restrict__ w1t,
                                              const float* __restrict__ w2,
                                              unsigned short* __restrict__ w2t) {
  __shared__ float tile[64][65];
  int b = blockIdx.x;
  int tid = threadIdx.x;
  if (b < 1024) {
    // ---- gate + x convert: one wave per token ----
    int t = b * 4 + (tid >> 6);
    int lane = tid & 63;
    const float4* xr = (const float4*)(x + (size_t)t * DIMX);
    ushort4* xo = (ushort4*)(xbf + (size_t)t * DIMX);
    float p[NE];
#pragma unroll
    for (int e = 0; e < NE; e++) p[e] = 0.f;
#pragma unroll
    for (int j = 0; j < 4; j++) {
      int idx4 = j * 64 + lane;
      float4 v = xr[idx4];
      ushort4 o; o.x = f2bf(v.x); o.y = f2bf(v.y); o.z = f2bf(v.z); o.w = f2bf(v.w);
      xo[idx4] = o;
      const float4* gp = (const float4*)(gw + (size_t)(idx4 * 4) * NE);
      float4 gA = gp[0], gB = gp[1], gC = gp[2], gD = gp[3];
      float4 gE = gp[4], gF = gp[5], gG = gp[6], gH = gp[7];
      p[0] += v.x * gA.x + v.y * gC.x + v.z * gE.x + v.w * gG.x;
      p[1] += v.x * gA.y + v.y * gC.y + v.z * gE.y + v.w * gG.y;
      p[2] += v.x * gA.z + v.y * gC.z + v.z * gE.z + v.w * gG.z;
      p[3] += v.x * gA.w + v.y * gC.w + v.z * gE.w + v.w * gG.w;
      p[4] += v.x * gB.x + v.y * gD.x + v.z * gF.x + v.w * gH.x;
      p[5] += v.x * gB.y + v.y * gD.y + v.z * gF.y + v.w * gH.y;
      p[6] += v.x * gB.z + v.y * gD.z + v.z * gF.z + v.w * gH.z;
      p[7] += v.x * gB.w + v.y * gD.w + v.z * gF.w + v.w * gH.w;
    }
#pragma unroll
    for (int e = 0; e < NE; e++)
#pragma unroll
      for (int off = 32; off > 0; off >>= 1) p[e] += __shfl_xor(p[e], off);
    if (lane == 0) {
      int ia = 0; float va = p[0];
#pragma unroll
      for (int e = 1; e < NE; e++) if (p[e] > va) { va = p[e]; ia = e; }
      int ib = -1; float vb = -3.0e38f;
#pragma unroll
      for (int e = 0; e < NE; e++) { if (e == ia) continue; if (p[e] > vb) { vb = p[e]; ib = e; } }
      float w0 = 1.f / (1.f + expf(vb - va));
      ti[t * 2] = ia;     tw[t * 2] = w0;
      ti[t * 2 + 1] = ib; tw[t * 2 + 1] = 1.f - w0;
    }
    return;
  }
  // ---- transpose+convert segment: out[c][r] = bf16(in[r][c]) ----
  const float* in; unsigned short* outp; int R, C, c0, r0;
  if (b < 1024 + 4096) {
    int idx = b - 1024;                 // w1: R=DIMX, C=HID; 8e x 16r x 32c
    R = DIMX; C = HID;
    int e = idx >> 9;
    c0 = (idx & 31) * 64;
    r0 = ((idx >> 5) & 15) * 64;
    in = w1 + (size_t)e * R * C;
    outp = w1t + (size_t)e * R * C;
  } else {
    int idx = b - 5120;                 // w2: R=HID, C=DIMX; 8e x 32r x 16c
    R = HID; C = DIMX;
    int e = idx >> 9;
    c0 = (idx & 15) * 64;
    r0 = ((idx >> 4) & 31) * 64;
    in = w2 + (size_t)e * R * C;
    outp = w2t + (size_t)e * R * C;
  }
  {
    int tx = tid & 15, ty = tid >> 4;
#pragma unroll
    for (int i = 0; i < 4; i++) {
      int row = ty + i * 16;
      float4 v = *(const float4*)(in + (size_t)(r0 + row) * C + c0 + tx * 4);
      tile[row][tx * 4] = v.x; tile[row][tx * 4 + 1] = v.y;
      tile[row][tx * 4 + 2] = v.z; tile[row][tx * 4 + 3] = v.w;
    }
    __syncthreads();
    // writer: 16B/lane stores. lane group (tid&7) covers 8 consecutive rows.
    int r_off = (tid & 7) * 8;
    int ccb = tid >> 3;                 // 0..31
#pragma unroll
    for (int i = 0; i < 2; i++) {
      int cc = ccb + i * 32;
      unsigned short o[8];
#pragma unroll
      for (int j = 0; j < 8; j++) o[j] = f2bf(tile[r_off + j][cc]);
      *(int4*)(outp + (size_t)(c0 + cc) * R + r0 + r_off) = *(const int4*)o;
    }
  }
}

// single block; ti AND tw staged in LDS -> zero global loads in the compaction loop
__global__ __launch_bounds__(512) void k_build(const int* __restrict__ ti,
                                               const float* __restrict__ tw,
                                               int* __restrict__ cnt,
                                               int* __restrict__ poffs,
                                               int* __restrict__ s_e, int* __restrict__ s_r0,
                                               int* __restrict__ ptok, int* __restrict__ ptk,
                                               float* __restrict__ pw) {
  __shared__ int sti[NPAIR];
  __shared__ float stw[NPAIR];
  __shared__ int scnt[NE];
  for (int i = threadIdx.x; i < NPAIR; i += 512) { sti[i] = ti[i]; stw[i] = tw[i]; }
  __syncthreads();
  int wid = threadIdx.x >> 6;
  int lane = threadIdx.x & 63;
  int c = 0;
  for (int p = lane; p < NPAIR; p += 64) c += (sti[p] == wid) ? 1 : 0;
#pragma unroll
  for (int off = 32; off > 0; off >>= 1) c += __shfl_xor(c, off);
  if (lane == 0) scnt[wid] = c;
  __syncthreads();
  if (threadIdx.x == 0) {
    int s = 0, pacc = 0;
    for (int e = 0; e < NE; e++) {
      cnt[e] = scnt[e];
      poffs[e] = pacc;
      int ns = (scnt[e] + 127) >> 7;
      for (int k = 0; k < ns; k++) { s_e[s] = e; s_r0[s] = k * 128; s++; }
      pacc += ns * 128;
    }
    poffs[NE] = pacc;
    for (; s < MAXSTRIP; s++) { s_e[s] = -1; s_r0[s] = 0; }
  }
  int base = 0;
  for (int p0 = 0; p0 < NPAIR; p0 += 64) {
    int p = p0 + lane;
    bool m = (sti[p] == wid);
    unsigned long long mask = __ballot(m);
    if (m) {
      int pos = base + __popcll(mask & ((1ull << lane) - 1ull));
      ptok[wid * NT + pos] = p >> 1;
      ptk[wid * NT + pos] = p;
      pw[wid * NT + pos] = stw[p];
    }
    base += __popcll(mask);
  }
}

#define BM 128
#define BN 128
#define BK 32
// R16: GEMMs at measured-best R12 config (67 µs each, FETCH 57 MB): BK=32,
// 3-buffer LDS (48 KB), single barrier per K-step, counted vmcnt(4),
// depth-1 prefetch, setprio around MFMA. BK=64 measured WORSE (70 µs,
// FETCH 72 MB, occupancy 14%): per-step cost scales with work.
// Conflict-free swizzle on 64B rows: store chunk = c ^ ((row>>1)&3),
// read chunk = quad ^ ((m16>>1)&3). XCD swizzle: 72 strips = 9/XCD.
#define KSTEPS 32

// GEMM1: hpre[poffs[e]+g][:] = gathered_x[tok] @ w1T[e]^T + b1[e]
__global__ __launch_bounds__(256) void k_gemm1(
    const unsigned short* __restrict__ xbf,
    const unsigned short* __restrict__ w1t,
    const float* __restrict__ bias1,
    const int* __restrict__ cnt, const int* __restrict__ s_e,
    const int* __restrict__ s_r0, const int* __restrict__ poffs,
    const int* __restrict__ ptok,
    unsigned short* __restrict__ hpre)
{
  int lid = blockIdx.x + 16 * blockIdx.y;      // 0..1151, hw linear order
  int xcd = lid & 7;
  int t4 = lid >> 3;                           // 0..143
  int colb = t4 & 15;
  int s = xcd * 9 + (t4 >> 4);                 // strip
  int e = s_e[s];
  if (e < 0) return;
  int r0e = s_r0[s];
  int n_e = cnt[e];
  int pbase = poffs[e];
  int col0 = colb * BN;

  __shared__ __align__(16) unsigned short As[3][BM][BK];
  __shared__ __align__(16) unsigned short Bs[3][BN][BK];

  int tid = threadIdx.x;
  int lane = tid & 63, wid = tid >> 6;
  int wr = wid >> 1, wc = wid & 1;
  int quad = lane >> 4, m16 = lane & 15;

  int rr = lane >> 2;
  int csrc = ((lane & 3) ^ ((lane >> 3) & 3)) * 8;
  int ga0 = r0e + wid * 32 + rr;      if (ga0 >= n_e) ga0 = n_e - 1;
  int ga1 = r0e + wid * 32 + 16 + rr; if (ga1 >= n_e) ga1 = n_e - 1;
  int t0 = ptok[e * NT + ga0];
  int t1 = ptok[e * NT + ga1];
  const unsigned short* a0p = xbf + (size_t)t0 * DIMX + csrc;
  const unsigned short* a1p = xbf + (size_t)t1 * DIMX + csrc;
  const unsigned short* bbase = w1t + (size_t)e * HID * DIMX;
  const unsigned short* b0p = bbase + (size_t)(col0 + wid * 32 + rr) * DIMX + csrc;
  const unsigned short* b1p = bbase + (size_t)(col0 + wid * 32 + 16 + rr) * DIMX + csrc;

  int ca = (quad ^ ((m16 >> 1) & 3)) * 8;

  f32x4 acc[4][4];
#pragma unroll
  for (int i = 0; i < 4; i++)
#pragma unroll
    for (int j = 0; j < 4; j++) acc[i][j] = (f32x4)(0.f);

#define STAGE1(b, kk) do { \
    gload_lds16(a0p + (kk), &As[b][wid * 32][0]); \
    gload_lds16(a1p + (kk), &As[b][wid * 32 + 16][0]); \
    gload_lds16(b0p + (kk), &Bs[b][wid * 32][0]); \
    gload_lds16(b1p + (kk), &Bs[b][wid * 32 + 16][0]); \
  } while (0)

  STAGE1(0, 0);
  int cur = 0;
  for (int k = 0; k < KSTEPS; ++k) {
    int nxt = (cur == 2) ? 0 : cur + 1;
    if (k + 1 < KSTEPS) {
      STAGE1(nxt, (k + 1) * BK);
      asm volatile("s_waitcnt vmcnt(4)" ::: "memory");   // buf[cur] landed (in-order)
    } else {
      asm volatile("s_waitcnt vmcnt(0)" ::: "memory");
    }
    asm volatile("s_waitcnt lgkmcnt(0)" ::: "memory");   // my prior ds_reads retired
    __builtin_amdgcn_sched_barrier(0);
    __builtin_amdgcn_s_barrier();            // publish buf[cur] block-wide
    __builtin_amdgcn_sched_barrier(0);
    bf16x8 af[4], bfr[4];
#pragma unroll
    for (int i = 0; i < 4; i++) af[i]  = *(const bf16x8*)&As[cur][wr * 64 + i * 16 + m16][ca];
#pragma unroll
    for (int j = 0; j < 4; j++) bfr[j] = *(const bf16x8*)&Bs[cur][wc * 64 + j * 16 + m16][ca];
    __builtin_amdgcn_s_setprio(1);
#pragma unroll
    for (int i = 0; i < 4; i++)
#pragma unroll
      for (int j = 0; j < 4; j++)
        acc[i][j] = __builtin_amdgcn_mfma_f32_16x16x32_bf16(af[i], bfr[j], acc[i][j], 0, 0, 0);
    __builtin_amdgcn_s_setprio(0);
    cur = nxt;
  }
#undef STAGE1

  float bj[4];
#pragma unroll
  for (int j = 0; j < 4; j++) bj[j] = bias1[e * HID + col0 + wc * 64 + j * 16 + m16];
#pragma unroll
  for (int i = 0; i < 4; i++) {
#pragma unroll
    for (int r = 0; r < 4; r++) {
      int g = r0e + wr * 64 + i * 16 + quad * 4 + r;
      if (g < n_e) {
        size_t rowbase = (size_t)(pbase + g) * HID;
#pragma unroll
        for (int j = 0; j < 4; j++) {
          int colg = col0 + wc * 64 + j * 16 + m16;
          hpre[rowbase + colg] = f2bf(acc[i][j][r] + bj[j]);
        }
      }
    }
  }
}

// one wave per row: LayerNorm + exact GELU over HID, no barriers
__global__ __launch_bounds__(256) void k_ln_gelu(unsigned short* __restrict__ h,
                                                 const float* __restrict__ g1,
                                                 const float* __restrict__ bb1,
                                                 const int* __restrict__ s_e) {
  int row = blockIdx.x * 4 + (threadIdx.x >> 6);
  int e = s_e[row >> 7];
  if (e < 0) return;
  int lane = threadIdx.x & 63;
  unsigned short* p = h + (size_t)row * HID;
  int4* p4 = (int4*)p;                 // 8 bf16 per int4; 256 per row
  int4 raw[4];
#pragma unroll
  for (int sg = 0; sg < 4; sg++) raw[sg] = p4[sg * 64 + lane];
  float v[32];
#pragma unroll
  for (int sg = 0; sg < 4; sg++) {
    const unsigned short* u = (const unsigned short*)&raw[sg];
#pragma unroll
    for (int k = 0; k < 8; k++) v[sg * 8 + k] = bf2f(u[k]);
  }
  float s = 0.f;
#pragma unroll
  for (int i = 0; i < 32; i++) s += v[i];
#pragma unroll
  for (int off = 32; off > 0; off >>= 1) s += __shfl_xor(s, off);
  float mean = s * (1.f / HID);
  float sq = 0.f;
#pragma unroll
  for (int i = 0; i < 32; i++) { float d = v[i] - mean; sq += d * d; }
#pragma unroll
  for (int off = 32; off > 0; off >>= 1) sq += __shfl_xor(sq, off);
  float rstd = rsqrtf(sq * (1.f / HID) + 1e-5f);
  const float4* gg = (const float4*)(g1 + (size_t)e * HID);
  const float4* gb = (const float4*)(bb1 + (size_t)e * HID);
#pragma unroll
  for (int sg = 0; sg < 4; sg++) {
    float4 ga = gg[sg * 128 + lane * 2], gc = gg[sg * 128 + lane * 2 + 1];
    float4 ba = gb[sg * 128 + lane * 2], bc = gb[sg * 128 + lane * 2 + 1];
    float gn[8] = {ga.x, ga.y, ga.z, ga.w, gc.x, gc.y, gc.z, gc.w};
    float bn[8] = {ba.x, ba.y, ba.z, ba.w, bc.x, bc.y, bc.z, bc.w};
    unsigned short o[8];
#pragma unroll
    for (int k = 0; k < 8; k++) {
      float xn = (v[sg * 8 + k] - mean) * rstd * gn[k] + bn[k];
      float ge = 0.5f * xn * (1.f + erff(xn * 0.7071067811865476f));
      o[k] = f2bf(ge);
    }
    p4[sg * 64 + lane] = *(const int4*)o;
  }
}

// GEMM2 (split-K x2): partial[ks][ptk] = (h_row @ w2T[e][:, ks*1024:+1024]^T
//                                          + (ks==1 ? b2[e] : 0)) * gate_weight
__global__ __launch_bounds__(256) void k_gemm2(
    const unsigned short* __restrict__ hb,
    const unsigned short* __restrict__ w2t,
    const float* __restrict__ bias2,
    const int* __restrict__ cnt, const int* __restrict__ s_e,
    const int* __restrict__ s_r0, const int* __restrict__ poffs,
    const int* __restrict__ ptk, const float* __restrict__ pw,
    float* __restrict__ ybufA, float* __restrict__ ybufB)
{
  int lid = blockIdx.x + 8 * (blockIdx.y + 72 * blockIdx.z);
  int xcd = lid & 7;
  int t4 = lid >> 3;                  // 0..143
  int colb = t4 & 7;
  int rem = t4 >> 3;                  // 0..17
  int ks = rem & 1;
  int s = xcd * 9 + (rem >> 1);       // strip
  int e = s_e[s];
  if (e < 0) return;
  int r0e = s_r0[s];
  int n_e = cnt[e];
  int pbase = poffs[e];
  int col0 = colb * BN;
  int kbase = ks << 10;               // element offset into K=2048

  __shared__ __align__(16) unsigned short As[3][BM][BK];
  __shared__ __align__(16) unsigned short Bs[3][BN][BK];

  int tid = threadIdx.x;
  int lane = tid & 63, wid = tid >> 6;
  int wr = wid >> 1, wc = wid & 1;
  int quad = lane >> 4, m16 = lane & 15;

  int rr = lane >> 2;
  int csrc = ((lane & 3) ^ ((lane >> 3) & 3)) * 8;
  int ga0 = r0e + wid * 32 + rr;      if (ga0 >= n_e) ga0 = n_e - 1;
  int ga1 = r0e + wid * 32 + 16 + rr; if (ga1 >= n_e) ga1 = n_e - 1;
  const unsigned short* a0p = hb + (size_t)(pbase + ga0) * HID + kbase + csrc;
  const unsigned short* a1p = hb + (size_t)(pbase + ga1) * HID + kbase + csrc;
  const unsigned short* bbase = w2t + (size_t)e * DIMX * HID;
  const unsigned short* b0p = bbase + (size_t)(col0 + wid * 32 + rr) * HID + kbase + csrc;
  const unsigned short* b1p = bbase + (size_t)(col0 + wid * 32 + 16 + rr) * HID + kbase + csrc;

  int ca = (quad ^ ((m16 >> 1) & 3)) * 8;

  f32x4 acc[4][4];
#pragma unroll
  for (int i = 0; i < 4; i++)
#pragma unroll
    for (int j = 0; j < 4; j++) acc[i][j] = (f32x4)(0.f);

#define STAGE2(b, kk) do { \
    gload_lds16(a0p + (kk), &As[b][wid * 32][0]); \
    gload_lds16(a1p + (kk), &As[b][wid * 32 + 16][0]); \
    gload_lds16(b0p + (kk), &Bs[b][wid * 32][0]); \
    gload_lds16(b1p + (kk), &Bs[b][wid * 32 + 16][0]); \
  } while (0)

  STAGE2(0, 0);
  int cur = 0;
  for (int k = 0; k < KSTEPS; ++k) {
    int nxt = (cur == 2) ? 0 : cur + 1;
    if (k + 1 < KSTEPS) {
      STAGE2(nxt, (k + 1) * BK);
      asm volatile("s_waitcnt vmcnt(4)" ::: "memory");
    } else {
      asm volatile("s_waitcnt vmcnt(0)" ::: "memory");
    }
    asm volatile("s_waitcnt lgkmcnt(0)" ::: "memory");
    __builtin_amdgcn_sched_barrier(0);
    __builtin_amdgcn_s_barrier();
    __builtin_amdgcn_sched_barrier(0);
    bf16x8 af[4], bfr[4];
#pragma unroll
    for (int i = 0; i < 4; i++) af[i]  = *(const bf16x8*)&As[cur][wr * 64 + i * 16 + m16][ca];
#pragma unroll
    for (int j = 0; j < 4; j++) bfr[j] = *(const bf16x8*)&Bs[cur][wc * 64 + j * 16 + m16][ca];
    __builtin_amdgcn_s_setprio(1);
#pragma unroll
    for (int i = 0; i < 4; i++)
#pragma unroll
      for (int j = 0; j < 4; j++)
        acc[i][j] = __builtin_amdgcn_mfma_f32_16x16x32_bf16(af[i], bfr[j], acc[i][j], 0, 0, 0);
    __builtin_amdgcn_s_setprio(0);
    cur = nxt;
  }
#undef STAGE2

  float* yb = ks ? ybufB : ybufA;
  float bj[4];
#pragma unroll
  for (int j = 0; j < 4; j++)
    bj[j] = ks ? bias2[e * DIMX + col0 + wc * 64 + j * 16 + m16] : 0.f;
#pragma unroll
  for (int i = 0; i < 4; i++) {
#pragma unroll
    for (int r = 0; r < 4; r++) {
      int g = r0e + wr * 64 + i * 16 + quad * 4 + r;
      if (g < n_e) {
        int pi = e * NT + g;
        float w = pw[pi];
        size_t obase = (size_t)ptk[pi] * DIMX;
#pragma unroll
        for (int j = 0; j < 4; j++) {
          int colg = col0 + wc * 64 + j * 16 + m16;
          yb[obase + colg] = (acc[i][j][r] + bj[j]) * w;
        }
      }
    }
  }
}

// one wave per token: out = LN(yA_s0 + yA_s1 + yB_s0 + yB_s1 + x), no barriers
__global__ __launch_bounds__(256) void k_final(const float* __restrict__ ybA,
                                               const float* __restrict__ ybB,
                                               const float* __restrict__ x,
                                               const float* __restrict__ lg,
                                               const float* __restrict__ lb,
                                               float* __restrict__ out) {
  int t = blockIdx.x * 4 + (threadIdx.x >> 6);
  int lane = threadIdx.x & 63;
  const float4* yA0 = (const float4*)(ybA + (size_t)t * 2 * DIMX);
  const float4* yA1 = yA0 + DIMX / 4;
  const float4* yB0 = (const float4*)(ybB + (size_t)t * 2 * DIMX);
  const float4* yB1 = yB0 + DIMX / 4;
  const float4* x4 = (const float4*)(x + (size_t)t * DIMX);
  float4 v[4];
  float s = 0.f;
#pragma unroll
  for (int sg = 0; sg < 4; sg++) {
    int idx = sg * 64 + lane;
    float4 a = yA0[idx], b = yA1[idx], a2 = yB0[idx], b2 = yB1[idx], c = x4[idx];
    v[sg].x = a.x + b.x + a2.x + b2.x + c.x;
    v[sg].y = a.y + b.y + a2.y + b2.y + c.y;
    v[sg].z = a.z + b.z + a2.z + b2.z + c.z;
    v[sg].w = a.w + b.w + a2.w + b2.w + c.w;
    s += v[sg].x + v[sg].y + v[sg].z + v[sg].w;
  }
#pragma unroll
  for (int off = 32; off > 0; off >>= 1) s += __shfl_xor(s, off);
  float mean = s * (1.f / DIMX);
  float sq = 0.f;
#pragma unroll
  for (int sg = 0; sg < 4; sg++) {
    float dx = v[sg].x - mean, dy = v[sg].y - mean, dz = v[sg].z - mean, dw = v[sg].w - mean;
    sq += dx * dx + dy * dy + dz * dz + dw * dw;
  }
#pragma unroll
  for (int off = 32; off > 0; off >>= 1) sq += __shfl_xor(sq, off);
  float rstd = rsqrtf(sq * (1.f / DIMX) + 1e-5f);
  float4* o4 = (float4*)(out + (size_t)t * DIMX);
#pragma unroll
  for (int sg = 0; sg < 4; sg++) {
    int idx = sg * 64 + lane;
    float4 g = ((const float4*)lg)[idx], bb = ((const float4*)lb)[idx];
    float4 o;
    o.x = (v[sg].x - mean) * rstd * g.x + bb.x;
    o.y = (v[sg].y - mean) * rstd * g.y + bb.y;
    o.z = (v[sg].z - mean) * rstd * g.z + bb.z;
    o.w = (v[sg].w - mean) * rstd * g.w + bb.w;
    o4[idx] = o;
  }
}

extern "C" void kernel_launch(void* const* d_in, const int* in_sizes, int n_in,
                              void* d_out, int out_size, void* d_ws, size_t ws_size,
                              hipStream_t stream) {
  const float* x     = (const float*)d_in[0];
  const float* gw    = (const float*)d_in[1];
  const float* w1    = (const float*)d_in[2];
  const float* b1    = (const float*)d_in[3];
  const float* ln1g  = (const float*)d_in[4];
  const float* ln1b  = (const float*)d_in[5];
  const float* w2    = (const float*)d_in[6];
  const float* b2    = (const float*)d_in[7];
  const float* lng   = (const float*)d_in[8];
  const float* lnb   = (const float*)d_in[9];
  float* out = (float*)d_out;

  char* ws = (char*)d_ws;
  int* cnt   = (int*)(ws + O_CNT);
  int* ptok  = (int*)(ws + O_TOK);
  int* ptk   = (int*)(ws + O_TK);
  float* pw  = (float*)(ws + O_PW);
  int* ti    = (int*)(ws + O_TI);
  float* tw  = (float*)(ws + O_TW);
  int* poffs = (int*)(ws + O_POFF);
  int* s_e   = (int*)(ws + O_SE);
  int* s_r0  = (int*)(ws + O_SR0);
  unsigned short* xbf  = (unsigned short*)(ws + O_XBF);
  unsigned short* w1t  = (unsigned short*)(ws + O_W1T);
  unsigned short* w2t  = (unsigned short*)(ws + O_W2T);
  unsigned short* hpre = (unsigned short*)(ws + O_H);
  float* ybufA = (float*)(ws + O_Y);
  float* ybufB = (float*)(ws + O_W1T);   // w1t dead after k_gemm1; exact-size alias

  hipLaunchKernelGGL(k_prep, dim3(1024 + 4096 + 4096), dim3(256), 0, stream,
                     x, gw, xbf, ti, tw, w1, w1t, w2, w2t);
  hipLaunchKernelGGL(k_build, dim3(1), dim3(512), 0, stream, ti, tw, cnt, poffs, s_e, s_r0,
                     ptok, ptk, pw);
  hipLaunchKernelGGL(k_gemm1, dim3(HID / BN, MAXSTRIP), dim3(256), 0, stream,
                     xbf, w1t, b1, cnt, s_e, s_r0, poffs, ptok, hpre);
  hipLaunchKernelGGL(k_ln_gelu, dim3(MAXSTRIP * BM / 4), dim3(256), 0, stream,
                     hpre, ln1g, ln1b, s_e);
  hipLaunchKernelGGL(k_gemm2, dim3(DIMX / BN, MAXSTRIP, 2), dim3(256), 0, stream,
                     hpre, w2t, b2, cnt, s_e, s_r0, poffs, ptk, pw, ybufA, ybufB);
  hipLaunchKernelGGL(k_final, dim3(NT / 4), dim3(256), 0, stream, ybufA, ybufB, x, lng, lnb, out);
}